// Round 7
// baseline (726.683 us; speedup 1.0000x reference)
//
#include <hip/hip_runtime.h>
#include <math.h>

#define EPS 1e-5f

// sizes
#define B_  128
#define T0_ 512
#define S_  30
#define F_  64
#define L1_ 254
#define L2_ 125
#define L3_ 61
#define L4_ 29
#define BS_ (B_*S_)     // 3840
#define N_  (B_*L4_)    // 3712
#define H_  128
#define NC_ 18
#define KFS 1920        // F_*S_

typedef __attribute__((ext_vector_type(8))) short short8;
typedef __attribute__((ext_vector_type(16))) float f32x16;

__device__ __forceinline__ uint32_t f2bf(float f) {
    uint32_t u = __float_as_uint(f);
    return (u + 0x7fffu + ((u >> 16) & 1u)) >> 16;
}

typedef const __attribute__((address_space(1))) uint32_t* gas_t;
typedef __attribute__((address_space(3))) uint32_t* las_t;
__device__ __forceinline__ void glds16(const void* g, void* l) {
    __builtin_amdgcn_global_load_lds((gas_t)g, (las_t)l, 16, 0, 0);
}

#define MFMA(a,b,c) __builtin_amdgcn_mfma_f32_32x32x16_bf16(a, b, c, 0, 0, 0)

union ABu { uint4 u; short8 s; };

// ---------------- weight prepack: frag-ready hi/lo bf16 planes ----------------
// layout per layer (81920 B): hi[20480 ushort] then lo[20480]; elem idx
// r = ((kh*4+ck)*2+chalf)*512 + f*8 + j  with  c = ck*16 + chalf*8 + j
__global__ __launch_bounds__(256) void prepack_kernel(
    const float* __restrict__ wcs, ushort* __restrict__ aw)
{
    int i = blockIdx.x*256 + threadIdx.x;          // 0..61439
    int l = i / 20480, r = i - l*20480;
    int j = r & 7, f = (r >> 3) & 63, g = r >> 9;
    int chalf = g & 1, ck = (g >> 1) & 3, kh = g >> 3;
    int c = ck*16 + chalf*8 + j;
    float w = wcs[l*20480 + f*320 + c*5 + kh];
    uint32_t h = f2bf(w);
    uint32_t lo = f2bf(w - __uint_as_float(h << 16));
    aw[l*40960 + r]         = (ushort)h;
    aw[l*40960 + 20480 + r] = (ushort)lo;
}

// A-fragments (one 32-f tile) from prepacked planes into VGPRs
__device__ __forceinline__ void load_areg(const ushort* __restrict__ aw_l,
                                          int f0, int tcol, int chalf,
                                          ABu* AH_, ABu* AL_)
{
    #pragma unroll
    for (int idx = 0; idx < 20; idx++) {
        int r = (idx*2 + chalf)*512 + (f0 + tcol)*8;
        AH_[idx].u = *(const uint4*)(aw_l + r);
        AL_[idx].u = *(const uint4*)(aw_l + 20480 + r);
    }
}

// one 32f x 32t tile, K = 64c x 5kh, 3-term split-bf16, A from VGPRs
__device__ __forceinline__ f32x16 conv_mm_reg(
    const ABu* AH_, const ABu* AL_,
    const ushort* __restrict__ Bh, const ushort* __restrict__ Bl,
    int t, int chalf)
{
    f32x16 acc;
    #pragma unroll
    for (int i = 0; i < 16; i++) acc[i] = 0.f;
    #pragma unroll
    for (int kh = 0; kh < 5; kh++) {
        int tp = 2*t + kh;
        int sw = (tp >> 3) & 7;
        const ushort* brh = Bh + tp*64;
        const ushort* brl = Bl + tp*64;
        #pragma unroll
        for (int ck = 0; ck < 4; ck++) {
            int idx = kh*4 + ck;
            int col = (((ck*2 + chalf) ^ sw) << 3);
            short8 BH = *(const short8*)(brh + col);
            short8 BL = *(const short8*)(brl + col);
            acc = MFMA(AH_[idx].s, BH, acc);
            acc = MFMA(AH_[idx].s, BL, acc);
            acc = MFMA(AL_[idx].s, BH, acc);
        }
    }
    return acc;
}

// ---------------- conv0 (fp32 exact) + conv1 (MFMA), 5 slices/block ----------------
__global__ __launch_bounds__(512, 2) void conv01_mfma(
    const float* __restrict__ x,  const float* __restrict__ w0,
    const ushort* __restrict__ aw, const float* __restrict__ cb,
    const float* __restrict__ bg, const float* __restrict__ bb,
    const float* __restrict__ bm, const float* __restrict__ bv,
    char* __restrict__ y1h, char* __restrict__ y1l)
{
    __shared__ ushort Yt[2][264*64];       // 67.6 KB
    __shared__ float xl[T0_];
    __shared__ float ep0[64], ep1[64], ep2[64];
    int tid = threadIdx.x;
    int lane = tid & 63, wv = tid >> 6;
    int tcol = lane & 31, chalf = lane >> 5;
    int f0 = (wv>>2)*32, t0 = (wv&3)*32, t = t0 + tcol;

    ABu AH_[20], AL_[20];
    load_areg(aw, f0, tcol, chalf, AH_, AL_);

    int cq = tid & 15, tpb = tid >> 4, c0 = cq*4;
    float w0r[20], inv0[4], add0[4], b0r[4];
    #pragma unroll
    for (int j = 0; j < 4; j++) {
        int c = c0 + j;
        #pragma unroll
        for (int u = 0; u < 5; u++) w0r[j*5+u] = w0[c*5+u];
        float iv = bg[c]*rsqrtf(bv[c]+EPS);
        inv0[j] = iv; add0[j] = bb[c]-bm[c]*iv; b0r[j] = cb[c];
    }
    if (tid < 64) {
        float iv = bg[64+tid]*rsqrtf(bv[64+tid]+EPS);
        ep0[tid] = iv; ep1[tid] = bb[64+tid]-bm[64+tid]*iv; ep2[tid] = cb[64+tid];
    }

    for (int sl = 0; sl < 5; sl++) {
        int bs = blockIdx.x*5 + sl, b = bs/S_, s = bs - b*S_;
        xl[tid] = x[(b*T0_ + tid)*S_ + s];
        __syncthreads();                       // xl ready; Yt free
        // conv0 -> relu -> bn -> hi/lo packed into Yt (thread = c-quad x t-row)
        #pragma unroll
        for (int k = 0; k < 9; k++) {
            int tp = tpb + k*32;
            if (tp < 264) {
                float v4[4];
                if (tp < L1_) {
                    float2 xa = *(const float2*)&xl[2*tp];
                    float2 xb = *(const float2*)&xl[2*tp+2];
                    float2 xc = *(const float2*)&xl[2*tp+4];
                    #pragma unroll
                    for (int j = 0; j < 4; j++) {
                        float a = b0r[j] + w0r[j*5]*xa.x + w0r[j*5+1]*xa.y
                                + w0r[j*5+2]*xb.x + w0r[j*5+3]*xb.y + w0r[j*5+4]*xc.x;
                        v4[j] = fmaxf(a, 0.f)*inv0[j] + add0[j];
                    }
                } else { v4[0]=v4[1]=v4[2]=v4[3]=0.f; }
                uint32_t h0=f2bf(v4[0]), h1=f2bf(v4[1]), h2=f2bf(v4[2]), h3=f2bf(v4[3]);
                uint2 H; H.x = h0|(h1<<16); H.y = h2|(h3<<16);
                uint2 L;
                L.x = f2bf(v4[0]-__uint_as_float(h0<<16)) | (f2bf(v4[1]-__uint_as_float(h1<<16))<<16);
                L.y = f2bf(v4[2]-__uint_as_float(h2<<16)) | (f2bf(v4[3]-__uint_as_float(h3<<16))<<16);
                int pos = tp*64 + (c0 ^ (((tp>>3)&7)<<3));
                *(uint2*)&Yt[0][pos] = H;
                *(uint2*)&Yt[1][pos] = L;
            }
        }
        __syncthreads();
        f32x16 acc = conv_mm_reg(AH_, AL_, Yt[0], Yt[1], t, chalf);
        __syncthreads();                       // Yt reads done; reuse as staging
        if (t < L2_) {
            int swzo = ((t>>1) ^ (t>>3)) & 7;
            #pragma unroll
            for (int rq = 0; rq < 4; rq++) {
                int fb = f0 + 8*rq + 4*chalf;
                uint32_t h[4], l[4];
                #pragma unroll
                for (int j = 0; j < 4; j++) {
                    int r = rq*4 + j, f = fb + j;
                    float val = fmaxf(acc[r]+ep2[f], 0.f)*ep0[f] + ep1[f];
                    h[j] = f2bf(val);
                    l[j] = f2bf(val - __uint_as_float(h[j]<<16));
                }
                int pos = ((((fb>>3) ^ swzo) << 3) + (fb & 7));
                uint2 H; H.x = h[0] | (h[1]<<16); H.y = h[2] | (h[3]<<16);
                uint2 L; L.x = l[0] | (l[1]<<16); L.y = l[2] | (l[3]<<16);
                *(uint2*)&Yt[0][t*64 + pos] = H;
                *(uint2*)&Yt[1][t*64 + pos] = L;
            }
        }
        __syncthreads();
        for (int i = tid; i < 2000; i += 512) {      // 125 rows x 8 chunks x 2 planes
            int pl = i >= 1000, jj = pl ? i-1000 : i;
            int tr = jj >> 3, p = jj & 7;
            int q = p ^ ((tr>>1) & 7);               // swz^swzo
            uint4 v = *(const uint4*)&Yt[pl][tr*64 + q*8];
            *(uint4*)((pl ? y1l : y1h) + (size_t)bs*16000 + tr*128 + p*16) = v;
        }
        // loop-top __syncthreads() protects Yt reuse
    }
}

// ---------------- conv2: 8 slices/block (4 iters x 2), dbuf prefetch ----------------
__global__ __launch_bounds__(512, 2) void conv2_mfma(
    const ushort* __restrict__ aw, const float* __restrict__ cb,
    const float* __restrict__ bg, const float* __restrict__ bb,
    const float* __restrict__ bm, const float* __restrict__ bv,
    char* __restrict__ yh, char* __restrict__ yl)
{
    __shared__ ushort Yt[2][2][2][132*64];   // [buf][slice][plane]  135 KB
    __shared__ float ep0[64], ep1[64], ep2[64];
    int tid = threadIdx.x;
    int lane = tid & 63, wv = tid >> 6;
    int tcol = lane & 31, chalf = lane >> 5;
    int slw = wv >> 2, f0 = ((wv>>1)&1)*32, t0 = (wv&1)*32, t = t0 + tcol;
    int blk = blockIdx.x;

    ABu AH_[20], AL_[20];
    load_areg(aw + 40960, f0, tcol, chalf, AH_, AL_);
    if (tid < 64) {
        float iv = bg[128+tid]*rsqrtf(bv[128+tid]+EPS);
        ep0[tid] = iv; ep1[tid] = bb[128+tid]-bm[128+tid]*iv; ep2[tid] = cb[128+tid];
    }
    // prologue: stage iter0 into buf0; zero rows 128..131 of both bufs
    #pragma unroll
    for (int sl2 = 0; sl2 < 2; sl2++)
        #pragma unroll
        for (int pl = 0; pl < 2; pl++) {
            const char* src = (pl ? yl : yh) + (size_t)(blk*8 + sl2)*16000;
            glds16(src + tid*16,        (char*)&Yt[0][sl2][pl][0] + (tid>>6)*1024);
            glds16(src + 8192 + tid*16, (char*)&Yt[0][sl2][pl][0] + 8192 + (tid>>6)*1024);
        }
    for (int i = tid; i < 1024; i += 512) {
        int g = i >> 7, w2 = i & 127;
        ((uint32_t*)&Yt[g>>2][(g>>1)&1][g&1][128*64])[w2] = 0;
    }
    __syncthreads();
    for (int i = tid; i < 384; i += 512) {        // zero rows 125..127 of buf0
        int g = i / 96, w2 = i - g*96;
        ((uint32_t*)&Yt[0][g>>1][g&1][125*64])[w2] = 0;
    }
    __syncthreads();

    for (int it = 0; it < 4; it++) {
        int buf = it & 1;
        int bs0 = blk*8 + it*2;
        if (it < 3) {                              // prefetch next pair (overlaps MFMA)
            #pragma unroll
            for (int sl2 = 0; sl2 < 2; sl2++)
                #pragma unroll
                for (int pl = 0; pl < 2; pl++) {
                    const char* src = (pl ? yl : yh) + (size_t)(bs0 + 2 + sl2)*16000;
                    glds16(src + tid*16,        (char*)&Yt[buf^1][sl2][pl][0] + (tid>>6)*1024);
                    glds16(src + 8192 + tid*16, (char*)&Yt[buf^1][sl2][pl][0] + 8192 + (tid>>6)*1024);
                }
        }
        f32x16 acc = conv_mm_reg(AH_, AL_, Yt[buf][slw][0], Yt[buf][slw][1], t, chalf);
        __syncthreads();                           // MFMA reads done; prefetch landed
        if (it < 3) {
            for (int i = tid; i < 384; i += 512) { // zero rows 125..127 of next buf
                int g = i / 96, w2 = i - g*96;
                ((uint32_t*)&Yt[buf^1][g>>1][g&1][125*64])[w2] = 0;
            }
        }
        if (t < L3_) {
            int swzo = ((t>>1) ^ (t>>3)) & 7;
            #pragma unroll
            for (int rq = 0; rq < 4; rq++) {
                int fb = f0 + 8*rq + 4*chalf;
                uint32_t h[4], l[4];
                #pragma unroll
                for (int j = 0; j < 4; j++) {
                    int r = rq*4 + j, f = fb + j;
                    float val = fmaxf(acc[r]+ep2[f], 0.f)*ep0[f] + ep1[f];
                    h[j] = f2bf(val);
                    l[j] = f2bf(val - __uint_as_float(h[j]<<16));
                }
                int pos = ((((fb>>3) ^ swzo) << 3) + (fb & 7));
                uint2 H; H.x = h[0] | (h[1]<<16); H.y = h[2] | (h[3]<<16);
                uint2 L; L.x = l[0] | (l[1]<<16); L.y = l[2] | (l[3]<<16);
                *(uint2*)&Yt[buf][slw][0][t*64 + pos] = H;
                *(uint2*)&Yt[buf][slw][1][t*64 + pos] = L;
            }
        }
        __syncthreads();
        for (int i = tid; i < 1952; i += 512) {    // 2sl x 2pl x 61 x 8
            int s2 = i / 976, r2 = i - s2*976;
            int pl = r2 >= 488, jj = pl ? r2-488 : r2;
            int tr = jj >> 3, p = jj & 7;
            int q = p ^ ((tr>>1) & 7);
            uint4 v = *(const uint4*)&Yt[buf][s2][pl][tr*64 + q*8];
            *(uint4*)((pl ? yl : yh) + (size_t)(bs0+s2)*16000 + tr*128 + p*16) = v;   // in-place y2
        }
        __syncthreads();                           // stores done before buf re-staged
    }
}

// ---------------- conv3: 8 slices/block (2 iters x 4), dbuf prefetch, fp32 out ----------------
__global__ __launch_bounds__(512, 2) void conv3_mfma(
    const ushort* __restrict__ aw, const float* __restrict__ cb,
    const float* __restrict__ bg, const float* __restrict__ bb,
    const float* __restrict__ bm, const float* __restrict__ bv,
    const char* __restrict__ yh, const char* __restrict__ yl,
    float* __restrict__ y3)
{
    __shared__ ushort Yt[2][4][2][68*64];   // 139.3 KB
    __shared__ float ep0[64], ep1[64], ep2[64];
    int tid = threadIdx.x;
    int lane = tid & 63, wv = tid >> 6;
    int tcol = lane & 31, chalf = lane >> 5;
    int slq = wv >> 1, f0 = (wv&1)*32, t = tcol;
    int blk = blockIdx.x;

    ABu AH_[20], AL_[20];
    load_areg(aw + 81920, f0, tcol, chalf, AH_, AL_);
    if (tid < 64) {
        float iv = bg[192+tid]*rsqrtf(bv[192+tid]+EPS);
        ep0[tid] = iv; ep1[tid] = bb[192+tid]-bm[192+tid]*iv; ep2[tid] = cb[192+tid];
    }
    // prologue: stage iter0 into buf0; zero rows 64..67 of both bufs
    #pragma unroll
    for (int sl2 = 0; sl2 < 4; sl2++)
        #pragma unroll
        for (int pl = 0; pl < 2; pl++) {
            const char* src = (pl ? yl : yh) + (size_t)(blk*8 + sl2)*16000;
            glds16(src + tid*16, (char*)&Yt[0][sl2][pl][0] + (tid>>6)*1024);
        }
    for (int i = tid; i < 2048; i += 512) {
        int g = i >> 7, w2 = i & 127;
        ((uint32_t*)&Yt[g>>3][(g>>1)&3][g&1][64*64])[w2] = 0;
    }
    __syncthreads();
    for (int i = tid; i < 768; i += 512) {         // zero rows 61..63 of buf0
        int g = i / 96, w2 = i - g*96;
        ((uint32_t*)&Yt[0][g>>1][g&1][61*64])[w2] = 0;
    }
    __syncthreads();

    for (int it = 0; it < 2; it++) {
        int buf = it & 1;
        int bs0 = blk*8 + it*4;
        if (it < 1) {                              // prefetch next quad
            #pragma unroll
            for (int sl2 = 0; sl2 < 4; sl2++)
                #pragma unroll
                for (int pl = 0; pl < 2; pl++) {
                    const char* src = (pl ? yl : yh) + (size_t)(bs0 + 4 + sl2)*16000;
                    glds16(src + tid*16, (char*)&Yt[buf^1][sl2][pl][0] + (tid>>6)*1024);
                }
        }
        f32x16 acc = conv_mm_reg(AH_, AL_, Yt[buf][slq][0], Yt[buf][slq][1], t, chalf);
        if (t < L4_) {
            #pragma unroll
            for (int r = 0; r < 16; r++) {
                int f = f0 + (r&3) + 8*(r>>2) + 4*chalf;
                float val = fmaxf(acc[r]+ep2[f], 0.f)*ep0[f] + ep1[f];
                y3[((size_t)(bs0+slq)*F_ + f)*L4_ + t] = val;
            }
        }
        __syncthreads();                           // MFMA reads done; prefetch landed
        if (it < 1) {
            for (int i = tid; i < 768; i += 512) { // zero rows 61..63 of next buf
                int g = i / 96, w2 = i - g*96;
                ((uint32_t*)&Yt[buf^1][g>>1][g&1][61*64])[w2] = 0;
            }
        }
        __syncthreads();
    }
}

// ---------------- y3 (b,s,f,l) -> xs (n=(b,l), f, s) tiled transpose ----------------
__global__ __launch_bounds__(256) void transp_kernel(
    const float* __restrict__ y3, float* __restrict__ xs)
{
    __shared__ float tl[15*F_*L4_];
    int b = blockIdx.x >> 1, s0 = (blockIdx.x & 1)*15;
    int tid = threadIdx.x;
    const float* src = y3 + (b*S_ + s0)*F_*L4_;
    for (int i = tid; i < 15*F_*L4_; i += 256) tl[i] = src[i];
    __syncthreads();
    for (int i = tid; i < L4_*F_*15; i += 256) {
        int l = i/(F_*15), f = (i/15)%F_, ss = i%15;
        xs[((b*L4_+l)*F_+f)*S_ + s0+ss] = tl[(ss*F_+f)*L4_ + l];
    }
}

// ---------------- self-attention per n slice (fp32, register-centric) ----------------
__global__ __launch_bounds__(256) void attn_kernel(
    const float* __restrict__ xsg, const float* __restrict__ wq,
    const float* __restrict__ wk,  const float* __restrict__ wv,
    const float* __restrict__ gam, float* __restrict__ seq)
{
    __shared__ float X[F_][32];        // cols 30,31 zeroed
    __shared__ float QKV[192][36];     // rows: Q 0..63, K 64..127, V 128..191
    __shared__ float BETA[S_][36];
    int n = blockIdx.x, tid = threadIdx.x;
    for (int i = tid; i < KFS; i += 256) X[i/S_][i%S_] = xsg[n*KFS + i];
    for (int i = tid; i < 128; i += 256) X[i>>1][30 + (i&1)] = 0.f;
    __syncthreads();
    if (tid < 192) {
        int wsel = tid >> 6, row = tid & 63;
        const float* W = (wsel==0) ? wq : (wsel==1) ? wk : wv;
        float4 wr_[16];
        #pragma unroll
        for (int u = 0; u < 16; u++) wr_[u] = ((const float4*)(W + row*64))[u];
        float acc[32];
        #pragma unroll
        for (int i = 0; i < 32; i++) acc[i] = 0.f;
        #pragma unroll
        for (int u = 0; u < 16; u++) {
            float4 w4 = wr_[u];
            #pragma unroll
            for (int c = 0; c < 4; c++) {
                float wv_ = (c==0) ? w4.x : (c==1) ? w4.y : (c==2) ? w4.z : w4.w;
                const float4* xr = (const float4*)&X[u*4+c][0];
                #pragma unroll
                for (int q = 0; q < 8; q++) {
                    float4 xq = xr[q];
                    acc[q*4+0] += wv_*xq.x; acc[q*4+1] += wv_*xq.y;
                    acc[q*4+2] += wv_*xq.z; acc[q*4+3] += wv_*xq.w;
                }
            }
        }
        #pragma unroll
        for (int q = 0; q < 8; q++) {
            float4 o4; o4.x=acc[q*4]; o4.y=acc[q*4+1]; o4.z=acc[q*4+2]; o4.w=acc[q*4+3];
            *(float4*)&QKV[tid][q*4] = o4;
        }
    }
    __syncthreads();
    if (tid < 240) {
        int j = tid >> 3, iq = tid & 7;
        float4 s4 = {0.f, 0.f, 0.f, 0.f};
        for (int o = 0; o < 64; o++) {
            float4 q4 = *(const float4*)&QKV[o][iq*4];
            float kv = QKV[64+o][j];
            s4.x += q4.x*kv; s4.y += q4.y*kv; s4.z += q4.z*kv; s4.w += q4.w*kv;
        }
        if (iq == 7) { s4.z = -1e30f; s4.w = -1e30f; }
        float m = fmaxf(fmaxf(s4.x, s4.y), fmaxf(s4.z, s4.w));
        m = fmaxf(m, __shfl_xor(m, 1, 8));
        m = fmaxf(m, __shfl_xor(m, 2, 8));
        m = fmaxf(m, __shfl_xor(m, 4, 8));
        float e0 = expf(s4.x-m), e1 = expf(s4.y-m), e2 = expf(s4.z-m), e3 = expf(s4.w-m);
        if (iq == 7) { e2 = 0.f; e3 = 0.f; }
        float sum = e0+e1+e2+e3;
        sum += __shfl_xor(sum, 1, 8);
        sum += __shfl_xor(sum, 2, 8);
        sum += __shfl_xor(sum, 4, 8);
        float inv = 1.f/sum;
        int i0 = iq*4;
        BETA[i0][j]   = e0*inv;
        BETA[i0+1][j] = e1*inv;
        if (iq < 7) { BETA[i0+2][j] = e2*inv; BETA[i0+3][j] = e3*inv; }
    }
    __syncthreads();
    {
        int f = tid >> 2, jh = tid & 3;
        float acc[8];
        #pragma unroll
        for (int i = 0; i < 8; i++) acc[i] = 0.f;
        for (int i = 0; i < S_; i++) {
            float v = QKV[128+f][i];
            float4 b0 = *(const float4*)&BETA[i][jh*8];
            float4 b1 = *(const float4*)&BETA[i][jh*8+4];
            acc[0] += v*b0.x; acc[1] += v*b0.y; acc[2] += v*b0.z; acc[3] += v*b0.w;
            acc[4] += v*b1.x; acc[5] += v*b1.y; acc[6] += v*b1.z; acc[7] += v*b1.w;
        }
        float g = gam[0];
        int j0 = jh*8;
        #pragma unroll
        for (int jj = 0; jj < 8; jj++) {
            int j = j0 + jj;
            if (j < S_) seq[n*KFS + f*S_ + j] = g*acc[jj] + X[f][j];
        }
    }
}

// ---------------- FC1: (3712,1920) @ (1920,128)^T + relu ----------------
__global__ __launch_bounds__(256) void fc1_kernel(
    const float* __restrict__ seq, const float* __restrict__ w,
    const float* __restrict__ bias, float* __restrict__ out)
{
    __shared__ float Sm[8*KFS];
    int n0 = blockIdx.x*8, tid = threadIdx.x;
    for (int i = tid; i < 8*KFS; i += 256) Sm[i] = seq[n0*KFS + i];
    __syncthreads();
    int h = tid & 127, rp = tid >> 7;
    float acc[4] = {0,0,0,0};
    const float4* wp = (const float4*)(w + h*KFS);
    #pragma unroll 4
    for (int k = 0; k < KFS/4; k++) {
        float4 wvv = wp[k];
        #pragma unroll
        for (int j = 0; j < 4; j++) {
            float4 sv = ((const float4*)&Sm[(rp*4+j)*KFS])[k];
            acc[j] += wvv.x*sv.x + wvv.y*sv.y + wvv.z*sv.z + wvv.w*sv.w;
        }
    }
    float bb2 = bias[h];
    #pragma unroll
    for (int j = 0; j < 4; j++)
        out[(n0 + rp*4 + j)*H_ + h] = fmaxf(acc[j] + bb2, 0.f);
}

// ---------------- 2-layer GRU + pred head ----------------
__global__ __launch_bounds__(768) void gru_kernel(
    const float* __restrict__ xin,  const float* __restrict__ wih,
    const float* __restrict__ whh,  const float* __restrict__ bih,
    const float* __restrict__ bhh,  const float* __restrict__ pw,
    const float* __restrict__ pb,   float* __restrict__ out)
{
    __shared__ float xh[H_], hh[H_], gi[3*H_], gh[3*H_], ys[L4_][H_];
    int b = blockIdx.x, tid = threadIdx.x;
    int mat = tid / 384, j = tid % 384;
    float4 wr[32];
    for (int layer = 0; layer < 2; layer++) {
        const float* wsrc = (mat ? whh : wih) + layer*384*128 + j*128;
        #pragma unroll
        for (int u = 0; u < 32; u++) wr[u] = ((const float4*)wsrc)[u];
        float bias = (mat ? bhh : bih)[layer*384 + j];
        if (tid < H_) hh[tid] = 0.f;
        __syncthreads();
        for (int t = 0; t < L4_; t++) {
            if (tid < H_) xh[tid] = (layer == 0) ? xin[(b*L4_+t)*H_ + tid] : ys[t][tid];
            __syncthreads();
            const float* src = mat ? hh : xh;
            float a0=0,a1=0,a2=0,a3=0;
            #pragma unroll
            for (int u = 0; u < 32; u++) {
                float4 xv = ((const float4*)src)[u];
                a0 += wr[u].x*xv.x; a1 += wr[u].y*xv.y;
                a2 += wr[u].z*xv.z; a3 += wr[u].w*xv.w;
            }
            float g = (a0+a1)+(a2+a3) + bias;
            if (mat) gh[j] = g; else gi[j] = g;
            __syncthreads();
            if (tid < H_) {
                int m = tid;
                float r = 1.f/(1.f+expf(-(gi[m]      + gh[m])));
                float z = 1.f/(1.f+expf(-(gi[m+128]  + gh[m+128])));
                float n = tanhf(gi[m+256] + r*gh[m+256]);
                float hnew = (1.f-z)*n + z*hh[m];
                hh[m] = hnew; ys[t][m] = hnew;
            }
            __syncthreads();
        }
    }
    if (tid < NC_) {
        float a = pb[tid];
        for (int k = 0; k < H_; k++) a += pw[tid*H_+k]*hh[k];
        out[b*NC_ + tid] = a;
    }
}

extern "C" void kernel_launch(void* const* d_in, const int* in_sizes, int n_in,
                              void* d_out, int out_size, void* d_ws, size_t ws_size,
                              hipStream_t stream) {
    const float* x    = (const float*)d_in[0];
    const float* w0   = (const float*)d_in[1];
    const float* wcs  = (const float*)d_in[2];
    const float* cb   = (const float*)d_in[3];
    const float* bg   = (const float*)d_in[4];
    const float* bb   = (const float*)d_in[5];
    const float* bm   = (const float*)d_in[6];
    const float* bv   = (const float*)d_in[7];
    const float* wq   = (const float*)d_in[8];
    const float* wk   = (const float*)d_in[9];
    const float* wv   = (const float*)d_in[10];
    const float* gam  = (const float*)d_in[11];
    const float* fw   = (const float*)d_in[12];
    const float* fb   = (const float*)d_in[13];
    const float* gwih = (const float*)d_in[14];
    const float* gwhh = (const float*)d_in[15];
    const float* gbih = (const float*)d_in[16];
    const float* gbhh = (const float*)d_in[17];
    const float* pw   = (const float*)d_in[18];
    const float* pb   = (const float*)d_in[19];
    float* out = (float*)d_out;
    uint32_t* wsu = (uint32_t*)d_ws;

    // workspace (4B word offsets):
    // aw (frag weights)       : 0        .. 61440
    // y1h planes (16000B/bs)  : 61440    .. +15,364,096   (y2 written in-place)
    // y1l planes              : 15425536 .. +15,364,096
    // P0 (y3 / seq)           : 30789632 .. +7,127,040
    // P1 (xs / f1)            : 37916672 .. +7,127,040
    ushort* aw  = (ushort*)wsu;
    char* y1h   = (char*)(wsu + 61440);
    char* y1l   = (char*)(wsu + 15425536);
    float* y3v  = (float*)(wsu + 30789632);
    float* seqv = (float*)(wsu + 30789632);
    float* xsv  = (float*)(wsu + 37916672);
    float* f1v  = (float*)(wsu + 37916672);

    prepack_kernel<<<240, 256, 0, stream>>>(wcs, aw);
    conv01_mfma<<<768, 512, 0, stream>>>(x, w0, aw, cb, bg, bb, bm, bv, y1h, y1l);
    conv2_mfma<<<480, 512, 0, stream>>>(aw, cb, bg, bb, bm, bv, y1h, y1l);
    conv3_mfma<<<480, 512, 0, stream>>>(aw, cb, bg, bb, bm, bv, y1h, y1l, y3v);
    transp_kernel<<<2*B_, 256, 0, stream>>>(y3v, xsv);
    attn_kernel<<<N_, 256, 0, stream>>>(xsv, wq, wk, wv, gam, seqv);
    fc1_kernel<<<N_/8, 256, 0, stream>>>(seqv, fw, fb, f1v);
    gru_kernel<<<B_, 768, 0, stream>>>(f1v, gwih, gwhh, gbih, gbhh, pw, pb, out);
}

// Round 8
// 678.304 us; speedup vs baseline: 1.0713x; 1.0713x over previous
//
#include <hip/hip_runtime.h>
#include <math.h>

#define EPS 1e-5f

// sizes
#define B_  128
#define T0_ 512
#define S_  30
#define F_  64
#define L1_ 254
#define L2_ 125
#define L3_ 61
#define L4_ 29
#define BS_ (B_*S_)     // 3840
#define N_  (B_*L4_)    // 3712
#define H_  128
#define NC_ 18
#define KFS 1920        // F_*S_

typedef __attribute__((ext_vector_type(8))) short short8;
typedef __attribute__((ext_vector_type(16))) float f32x16;

__device__ __forceinline__ uint32_t f2bf(float f) {
    uint32_t u = __float_as_uint(f);
    return (u + 0x7fffu + ((u >> 16) & 1u)) >> 16;
}

typedef const __attribute__((address_space(1))) uint32_t* gas_t;
typedef __attribute__((address_space(3))) uint32_t* las_t;
__device__ __forceinline__ void glds16(const void* g, void* l) {
    __builtin_amdgcn_global_load_lds((gas_t)g, (las_t)l, 16, 0, 0);
}

#define MFMA(a,b,c) __builtin_amdgcn_mfma_f32_32x32x16_bf16(a, b, c, 0, 0, 0)

union ABu { uint4 u; short8 s; };

// ---------------- weight prepack (unchanged layout) ----------------
__global__ __launch_bounds__(256) void prepack_kernel(
    const float* __restrict__ wcs, ushort* __restrict__ aw)
{
    int i = blockIdx.x*256 + threadIdx.x;          // 0..61439
    int l = i / 20480, r = i - l*20480;
    int j = r & 7, f = (r >> 3) & 63, g = r >> 9;
    int chalf = g & 1, ck = (g >> 1) & 3, kh = g >> 3;
    int c = ck*16 + chalf*8 + j;
    float w = wcs[l*20480 + f*320 + c*5 + kh];
    uint32_t h = f2bf(w);
    uint32_t lo = f2bf(w - __uint_as_float(h << 16));
    aw[l*40960 + r]         = (ushort)h;
    aw[l*40960 + 20480 + r] = (ushort)lo;
}

// A-fragments (one 32-f tile) into VGPRs
__device__ __forceinline__ void load_areg(const ushort* __restrict__ aw_l,
                                          int f0, int tcol, int chalf,
                                          ABu* AH_, ABu* AL_)
{
    #pragma unroll
    for (int idx = 0; idx < 20; idx++) {
        int r = (idx*2 + chalf)*512 + (f0 + tcol)*8;
        AH_[idx].u = *(const uint4*)(aw_l + r);
        AL_[idx].u = *(const uint4*)(aw_l + 20480 + r);
    }
}

// one 32f x 32t tile, K = 64c x 5kh, 3-term split-bf16, A from VGPRs
__device__ __forceinline__ f32x16 conv_mm_reg(
    const ABu* AH_, const ABu* AL_,
    const ushort* __restrict__ Bh, const ushort* __restrict__ Bl,
    int t, int chalf)
{
    f32x16 acc;
    #pragma unroll
    for (int i = 0; i < 16; i++) acc[i] = 0.f;
    #pragma unroll
    for (int kh = 0; kh < 5; kh++) {
        int tp = 2*t + kh;
        int sw = (tp >> 3) & 7;
        const ushort* brh = Bh + tp*64;
        const ushort* brl = Bl + tp*64;
        #pragma unroll
        for (int ck = 0; ck < 4; ck++) {
            int idx = kh*4 + ck;
            int col = (((ck*2 + chalf) ^ sw) << 3);
            short8 BH = *(const short8*)(brh + col);
            short8 BL = *(const short8*)(brl + col);
            acc = MFMA(AH_[idx].s, BH, acc);
            acc = MFMA(AH_[idx].s, BL, acc);
            acc = MFMA(AL_[idx].s, BH, acc);
        }
    }
    return acc;
}

// relu+bn epilogue, truncation hi/lo pack, write into Yt row t (swz = (t>>3)&7)
__device__ __forceinline__ void epi_pack_store(const f32x16& acc, int t, int f0, int chalf,
    const float* __restrict__ e0, const float* __restrict__ e1, const float* __restrict__ e2,
    ushort* __restrict__ Y0, ushort* __restrict__ Y1)
{
    int sw = (t >> 3) & 7;
    #pragma unroll
    for (int rq = 0; rq < 4; rq++) {
        int fb = f0 + 8*rq + 4*chalf;
        uint32_t u[4], r[4];
        #pragma unroll
        for (int j = 0; j < 4; j++) {
            int f = fb + j;
            float v = fmaxf(acc[rq*4+j] + e2[f], 0.f)*e0[f] + e1[f];
            u[j] = __float_as_uint(v);
            r[j] = __float_as_uint(v - __uint_as_float(u[j] & 0xffff0000u));
        }
        uint2 H, L;
        H.x = __builtin_amdgcn_perm(u[1], u[0], 0x07060302u);
        H.y = __builtin_amdgcn_perm(u[3], u[2], 0x07060302u);
        L.x = __builtin_amdgcn_perm(r[1], r[0], 0x07060302u);
        L.y = __builtin_amdgcn_perm(r[3], r[2], 0x07060302u);
        int pos = t*64 + (((fb >> 3) ^ sw) << 3) + (fb & 7);
        *(uint2*)&Y0[pos] = H;
        *(uint2*)&Y1[pos] = L;
    }
}

// ---------------- conv0 (scalar) + conv1 (MFMA), 256 thr, 5 slices/block ----------------
__global__ __launch_bounds__(256) void conv01_mfma(
    const float* __restrict__ x,  const float* __restrict__ w0,
    const ushort* __restrict__ aw, const float* __restrict__ cb,
    const float* __restrict__ bg, const float* __restrict__ bb,
    const float* __restrict__ bm, const float* __restrict__ bv,
    char* __restrict__ y1h, char* __restrict__ y1l)
{
    __shared__ ushort Yt[2][264*64];       // 67.6 KB
    __shared__ float xl[T0_];
    __shared__ float ep0[64], ep1[64], ep2[64];
    int tid = threadIdx.x;
    int lane = tid & 63, wv = tid >> 6;
    int tcol = lane & 31, chalf = lane >> 5;
    int f0 = (wv & 1)*32;
    int tA = (wv >> 1)*32 + tcol;          // round0: t 0..63
    int tB = tA + 64;                      // round1: t 64..127

    ABu AH_[20], AL_[20];
    load_areg(aw, f0, tcol, chalf, AH_, AL_);

    // conv0 persistents: 2 channels per thread
    int c2 = (tid & 31)*2, tq = tid >> 5;  // tq 0..7
    float w0p[10], bi[2], iv[2], ad[2];
    #pragma unroll
    for (int j = 0; j < 2; j++) {
        int c = c2 + j;
        #pragma unroll
        for (int u = 0; u < 5; u++) w0p[j*5+u] = w0[c*5+u];
        float v = bg[c]*rsqrtf(bv[c]+EPS);
        iv[j] = v; ad[j] = bb[c]-bm[c]*v; bi[j] = cb[c];
    }
    if (tid < 64) {
        float v = bg[64+tid]*rsqrtf(bv[64+tid]+EPS);
        ep0[tid] = v; ep1[tid] = bb[64+tid]-bm[64+tid]*v; ep2[tid] = cb[64+tid];
    }

    for (int sl = 0; sl < 5; sl++) {
        int bs = blockIdx.x*5 + sl, b = bs/S_, s = bs - b*S_;
        xl[tid]       = x[(b*T0_ + tid)*S_ + s];
        xl[tid + 256] = x[(b*T0_ + tid + 256)*S_ + s];
        __syncthreads();
        // conv0 -> relu -> bn -> hi/lo trunc-pack into Yt
        for (int k = 0; k < 33; k++) {
            int tp = tq + k*8;                      // 0..263
            uint32_t Hw = 0, Lw = 0;
            if (tp < L1_) {
                float2 xa = *(const float2*)&xl[2*tp];
                float2 xb = *(const float2*)&xl[2*tp+2];
                float xc = xl[2*tp+4];
                float v0 = bi[0] + w0p[0]*xa.x + w0p[1]*xa.y + w0p[2]*xb.x + w0p[3]*xb.y + w0p[4]*xc;
                float v1 = bi[1] + w0p[5]*xa.x + w0p[6]*xa.y + w0p[7]*xb.x + w0p[8]*xb.y + w0p[9]*xc;
                v0 = fmaxf(v0, 0.f)*iv[0] + ad[0];
                v1 = fmaxf(v1, 0.f)*iv[1] + ad[1];
                uint32_t u0 = __float_as_uint(v0), u1 = __float_as_uint(v1);
                Hw = __builtin_amdgcn_perm(u1, u0, 0x07060302u);
                uint32_t r0 = __float_as_uint(v0 - __uint_as_float(u0 & 0xffff0000u));
                uint32_t r1 = __float_as_uint(v1 - __uint_as_float(u1 & 0xffff0000u));
                Lw = __builtin_amdgcn_perm(r1, r0, 0x07060302u);
            }
            int pos = tp*64 + (c2 ^ (((tp>>3)&7) << 3));
            *(uint32_t*)&Yt[0][pos] = Hw;
            *(uint32_t*)&Yt[1][pos] = Lw;
        }
        __syncthreads();
        f32x16 acc0 = conv_mm_reg(AH_, AL_, Yt[0], Yt[1], tA, chalf);
        __syncthreads();
        // epi0 writes rows 0..63; round1 reads rows 128..258 (disjoint, no barrier)
        epi_pack_store(acc0, tA, f0, chalf, ep0, ep1, ep2, Yt[0], Yt[1]);
        f32x16 acc1 = conv_mm_reg(AH_, AL_, Yt[0], Yt[1], tB, chalf);
        if (tB < L2_) epi_pack_store(acc1, tB, f0, chalf, ep0, ep1, ep2, Yt[0], Yt[1]);
        __syncthreads();
        // copyout rows 0..127 (125..127 garbage; consumer zeroes), 2 planes
        for (int i = tid; i < 2048; i += 256) {
            int pl = i >> 10, jj = i & 1023;
            int tr = jj >> 3, p = jj & 7;
            uint4 v = *(const uint4*)&Yt[pl][tr*64 + p*8];
            *(uint4*)((pl ? y1l : y1h) + (size_t)bs*16384 + tr*128 + p*16) = v;
        }
        __syncthreads();
    }
}

// ---------------- conv2: 256 thr, 8 slices/block, dbuf prefetch ----------------
__global__ __launch_bounds__(256) void conv2_mfma(
    const ushort* __restrict__ aw, const float* __restrict__ cb,
    const float* __restrict__ bg, const float* __restrict__ bb,
    const float* __restrict__ bm, const float* __restrict__ bv,
    char* __restrict__ yh, char* __restrict__ yl)
{
    __shared__ ushort Yt[2][2][132*64];    // [buf][plane] 67.6 KB
    __shared__ float ep0[64], ep1[64], ep2[64];
    int tid = threadIdx.x;
    int lane = tid & 63, wv = tid >> 6;
    int tcol = lane & 31, chalf = lane >> 5;
    int f0 = (wv & 1)*32;
    int t = (wv >> 1)*32 + tcol;           // 0..63
    int blk = blockIdx.x;

    ABu AH_[20], AL_[20];
    load_areg(aw + 40960, f0, tcol, chalf, AH_, AL_);
    if (tid < 64) {
        float v = bg[128+tid]*rsqrtf(bv[128+tid]+EPS);
        ep0[tid] = v; ep1[tid] = bb[128+tid]-bm[128+tid]*v; ep2[tid] = cb[128+tid];
    }
    // prologue: stage slice0 -> buf0
    #pragma unroll
    for (int pl = 0; pl < 2; pl++) {
        const char* src = (pl ? yl : yh) + (size_t)(blk*8)*16384;
        #pragma unroll
        for (int k = 0; k < 4; k++)
            glds16(src + k*4096 + tid*16, (char*)&Yt[0][pl][0] + k*4096 + (tid>>6)*1024);
    }
    __syncthreads();
    for (int i = tid; i < 448; i += 256) {     // zero rows 125..131 of buf0
        int pl = i >= 224, jj = pl ? i-224 : i;
        ((uint32_t*)&Yt[0][pl][125*64])[jj] = 0;
    }
    __syncthreads();

    for (int it = 0; it < 8; it++) {
        int buf = it & 1;
        int bs = blk*8 + it;
        if (it < 7) {                           // prefetch next slice
            #pragma unroll
            for (int pl = 0; pl < 2; pl++) {
                const char* src = (pl ? yl : yh) + (size_t)(bs+1)*16384;
                #pragma unroll
                for (int k = 0; k < 4; k++)
                    glds16(src + k*4096 + tid*16, (char*)&Yt[buf^1][pl][0] + k*4096 + (tid>>6)*1024);
            }
        }
        f32x16 acc = conv_mm_reg(AH_, AL_, Yt[buf][0], Yt[buf][1], t, chalf);
        __syncthreads();                        // buf reads done; prefetch landed
        if (it < 7) {
            for (int i = tid; i < 448; i += 256) {
                int pl = i >= 224, jj = pl ? i-224 : i;
                ((uint32_t*)&Yt[buf^1][pl][125*64])[jj] = 0;
            }
        }
        if (t < L3_) epi_pack_store(acc, t, f0, chalf, ep0, ep1, ep2, Yt[buf][0], Yt[buf][1]);
        __syncthreads();
        for (int i = tid; i < 976; i += 256) {  // copyout rows 0..60, 2 planes (in-place y2)
            int pl = i >= 488, jj = pl ? i-488 : i;
            int tr = jj >> 3, p = jj & 7;
            uint4 v = *(const uint4*)&Yt[buf][pl][tr*64 + p*8];
            *(uint4*)((pl ? yl : yh) + (size_t)bs*16384 + tr*128 + p*16) = v;
        }
        __syncthreads();
    }
}

// ---------------- conv3: 256 thr, 8 slices/block (2/round), dbuf, fp32 out ----------------
__global__ __launch_bounds__(256) void conv3_mfma(
    const ushort* __restrict__ aw, const float* __restrict__ cb,
    const float* __restrict__ bg, const float* __restrict__ bb,
    const float* __restrict__ bm, const float* __restrict__ bv,
    const char* __restrict__ yh, const char* __restrict__ yl,
    float* __restrict__ y3)
{
    __shared__ ushort Yt[2][2][2][68*64];  // [buf][sl][plane] 69.6 KB
    __shared__ float ep0[64], ep1[64], ep2[64];
    int tid = threadIdx.x;
    int lane = tid & 63, wv = tid >> 6;
    int tcol = lane & 31, chalf = lane >> 5;
    int f0 = (wv & 1)*32, slw = wv >> 1, t = tcol;
    int blk = blockIdx.x;

    ABu AH_[20], AL_[20];
    load_areg(aw + 81920, f0, tcol, chalf, AH_, AL_);
    if (tid < 64) {
        float v = bg[192+tid]*rsqrtf(bv[192+tid]+EPS);
        ep0[tid] = v; ep1[tid] = bb[192+tid]-bm[192+tid]*v; ep2[tid] = cb[192+tid];
    }
    // prologue: stage slices 0,1 -> buf0 (rows 0..63)
    #pragma unroll
    for (int sl = 0; sl < 2; sl++)
        #pragma unroll
        for (int pl = 0; pl < 2; pl++) {
            const char* src = (pl ? yl : yh) + (size_t)(blk*8 + sl)*16384;
            #pragma unroll
            for (int k = 0; k < 2; k++)
                glds16(src + k*4096 + tid*16, (char*)&Yt[0][sl][pl][0] + k*4096 + (tid>>6)*1024);
        }
    __syncthreads();
    for (int i = tid; i < 896; i += 256) {     // zero rows 61..67 of buf0
        int g = i / 224, jj = i - g*224;       // g = sl*2+pl
        ((uint32_t*)&Yt[0][g>>1][g&1][61*64])[jj] = 0;
    }
    __syncthreads();

    for (int it = 0; it < 4; it++) {
        int buf = it & 1;
        int bs0 = blk*8 + it*2;
        if (it < 3) {
            #pragma unroll
            for (int sl = 0; sl < 2; sl++)
                #pragma unroll
                for (int pl = 0; pl < 2; pl++) {
                    const char* src = (pl ? yl : yh) + (size_t)(bs0 + 2 + sl)*16384;
                    #pragma unroll
                    for (int k = 0; k < 2; k++)
                        glds16(src + k*4096 + tid*16, (char*)&Yt[buf^1][sl][pl][0] + k*4096 + (tid>>6)*1024);
                }
        }
        f32x16 acc = conv_mm_reg(AH_, AL_, Yt[buf][slw][0], Yt[buf][slw][1], t, chalf);
        if (t < L4_) {
            #pragma unroll
            for (int r = 0; r < 16; r++) {
                int f = f0 + (r&3) + 8*(r>>2) + 4*chalf;
                float val = fmaxf(acc[r]+ep2[f], 0.f)*ep0[f] + ep1[f];
                y3[((size_t)(bs0+slw)*F_ + f)*L4_ + t] = val;
            }
        }
        __syncthreads();                        // buf reads done; prefetch landed
        if (it < 3) {
            for (int i = tid; i < 896; i += 256) {
                int g = i / 224, jj = i - g*224;
                ((uint32_t*)&Yt[buf^1][g>>1][g&1][61*64])[jj] = 0;
            }
        }
        __syncthreads();
    }
}

// ---------------- y3 (b,s,f,l) -> xs (n=(b,l), f, s) tiled transpose ----------------
__global__ __launch_bounds__(256) void transp_kernel(
    const float* __restrict__ y3, float* __restrict__ xs)
{
    __shared__ float tl[15*F_*L4_];
    int b = blockIdx.x >> 1, s0 = (blockIdx.x & 1)*15;
    int tid = threadIdx.x;
    const float* src = y3 + (b*S_ + s0)*F_*L4_;
    for (int i = tid; i < 15*F_*L4_; i += 256) tl[i] = src[i];
    __syncthreads();
    for (int i = tid; i < L4_*F_*15; i += 256) {
        int l = i/(F_*15), f = (i/15)%F_, ss = i%15;
        xs[((b*L4_+l)*F_+f)*S_ + s0+ss] = tl[(ss*F_+f)*L4_ + l];
    }
}

// ---------------- self-attention per n slice (fp32, register-centric) ----------------
__global__ __launch_bounds__(256) void attn_kernel(
    const float* __restrict__ xsg, const float* __restrict__ wq,
    const float* __restrict__ wk,  const float* __restrict__ wv,
    const float* __restrict__ gam, float* __restrict__ seq)
{
    __shared__ float X[F_][32];        // cols 30,31 zeroed
    __shared__ float QKV[192][36];     // rows: Q 0..63, K 64..127, V 128..191
    __shared__ float BETA[S_][36];
    int n = blockIdx.x, tid = threadIdx.x;
    for (int i = tid; i < KFS; i += 256) X[i/S_][i%S_] = xsg[n*KFS + i];
    for (int i = tid; i < 128; i += 256) X[i>>1][30 + (i&1)] = 0.f;
    __syncthreads();
    if (tid < 192) {
        int wsel = tid >> 6, row = tid & 63;
        const float* W = (wsel==0) ? wq : (wsel==1) ? wk : wv;
        float4 wr_[16];
        #pragma unroll
        for (int u = 0; u < 16; u++) wr_[u] = ((const float4*)(W + row*64))[u];
        float acc[32];
        #pragma unroll
        for (int i = 0; i < 32; i++) acc[i] = 0.f;
        #pragma unroll
        for (int u = 0; u < 16; u++) {
            float4 w4 = wr_[u];
            #pragma unroll
            for (int c = 0; c < 4; c++) {
                float wv_ = (c==0) ? w4.x : (c==1) ? w4.y : (c==2) ? w4.z : w4.w;
                const float4* xr = (const float4*)&X[u*4+c][0];
                #pragma unroll
                for (int q = 0; q < 8; q++) {
                    float4 xq = xr[q];
                    acc[q*4+0] += wv_*xq.x; acc[q*4+1] += wv_*xq.y;
                    acc[q*4+2] += wv_*xq.z; acc[q*4+3] += wv_*xq.w;
                }
            }
        }
        #pragma unroll
        for (int q = 0; q < 8; q++) {
            float4 o4; o4.x=acc[q*4]; o4.y=acc[q*4+1]; o4.z=acc[q*4+2]; o4.w=acc[q*4+3];
            *(float4*)&QKV[tid][q*4] = o4;
        }
    }
    __syncthreads();
    if (tid < 240) {
        int j = tid >> 3, iq = tid & 7;
        float4 s4 = {0.f, 0.f, 0.f, 0.f};
        for (int o = 0; o < 64; o++) {
            float4 q4 = *(const float4*)&QKV[o][iq*4];
            float kv = QKV[64+o][j];
            s4.x += q4.x*kv; s4.y += q4.y*kv; s4.z += q4.z*kv; s4.w += q4.w*kv;
        }
        if (iq == 7) { s4.z = -1e30f; s4.w = -1e30f; }
        float m = fmaxf(fmaxf(s4.x, s4.y), fmaxf(s4.z, s4.w));
        m = fmaxf(m, __shfl_xor(m, 1, 8));
        m = fmaxf(m, __shfl_xor(m, 2, 8));
        m = fmaxf(m, __shfl_xor(m, 4, 8));
        float e0 = expf(s4.x-m), e1 = expf(s4.y-m), e2 = expf(s4.z-m), e3 = expf(s4.w-m);
        if (iq == 7) { e2 = 0.f; e3 = 0.f; }
        float sum = e0+e1+e2+e3;
        sum += __shfl_xor(sum, 1, 8);
        sum += __shfl_xor(sum, 2, 8);
        sum += __shfl_xor(sum, 4, 8);
        float inv = 1.f/sum;
        int i0 = iq*4;
        BETA[i0][j]   = e0*inv;
        BETA[i0+1][j] = e1*inv;
        if (iq < 7) { BETA[i0+2][j] = e2*inv; BETA[i0+3][j] = e3*inv; }
    }
    __syncthreads();
    {
        int f = tid >> 2, jh = tid & 3;
        float acc[8];
        #pragma unroll
        for (int i = 0; i < 8; i++) acc[i] = 0.f;
        for (int i = 0; i < S_; i++) {
            float v = QKV[128+f][i];
            float4 b0 = *(const float4*)&BETA[i][jh*8];
            float4 b1 = *(const float4*)&BETA[i][jh*8+4];
            acc[0] += v*b0.x; acc[1] += v*b0.y; acc[2] += v*b0.z; acc[3] += v*b0.w;
            acc[4] += v*b1.x; acc[5] += v*b1.y; acc[6] += v*b1.z; acc[7] += v*b1.w;
        }
        float g = gam[0];
        int j0 = jh*8;
        #pragma unroll
        for (int jj = 0; jj < 8; jj++) {
            int j = j0 + jj;
            if (j < S_) seq[n*KFS + f*S_ + j] = g*acc[jj] + X[f][j];
        }
    }
}

// ---------------- FC1: (3712,1920) @ (1920,128)^T + relu ----------------
__global__ __launch_bounds__(256) void fc1_kernel(
    const float* __restrict__ seq, const float* __restrict__ w,
    const float* __restrict__ bias, float* __restrict__ out)
{
    __shared__ float Sm[8*KFS];
    int n0 = blockIdx.x*8, tid = threadIdx.x;
    for (int i = tid; i < 8*KFS; i += 256) Sm[i] = seq[n0*KFS + i];
    __syncthreads();
    int h = tid & 127, rp = tid >> 7;
    float acc[4] = {0,0,0,0};
    const float4* wp = (const float4*)(w + h*KFS);
    #pragma unroll 4
    for (int k = 0; k < KFS/4; k++) {
        float4 wvv = wp[k];
        #pragma unroll
        for (int j = 0; j < 4; j++) {
            float4 sv = ((const float4*)&Sm[(rp*4+j)*KFS])[k];
            acc[j] += wvv.x*sv.x + wvv.y*sv.y + wvv.z*sv.z + wvv.w*sv.w;
        }
    }
    float bb2 = bias[h];
    #pragma unroll
    for (int j = 0; j < 4; j++)
        out[(n0 + rp*4 + j)*H_ + h] = fmaxf(acc[j] + bb2, 0.f);
}

// ---------------- 2-layer GRU + pred head ----------------
__global__ __launch_bounds__(768) void gru_kernel(
    const float* __restrict__ xin,  const float* __restrict__ wih,
    const float* __restrict__ whh,  const float* __restrict__ bih,
    const float* __restrict__ bhh,  const float* __restrict__ pw,
    const float* __restrict__ pb,   float* __restrict__ out)
{
    __shared__ float xh[H_], hh[H_], gi[3*H_], gh[3*H_], ys[L4_][H_];
    int b = blockIdx.x, tid = threadIdx.x;
    int mat = tid / 384, j = tid % 384;
    float4 wr[32];
    for (int layer = 0; layer < 2; layer++) {
        const float* wsrc = (mat ? whh : wih) + layer*384*128 + j*128;
        #pragma unroll
        for (int u = 0; u < 32; u++) wr[u] = ((const float4*)wsrc)[u];
        float bias = (mat ? bhh : bih)[layer*384 + j];
        if (tid < H_) hh[tid] = 0.f;
        __syncthreads();
        for (int t = 0; t < L4_; t++) {
            if (tid < H_) xh[tid] = (layer == 0) ? xin[(b*L4_+t)*H_ + tid] : ys[t][tid];
            __syncthreads();
            const float* src = mat ? hh : xh;
            float a0=0,a1=0,a2=0,a3=0;
            #pragma unroll
            for (int u = 0; u < 32; u++) {
                float4 xv = ((const float4*)src)[u];
                a0 += wr[u].x*xv.x; a1 += wr[u].y*xv.y;
                a2 += wr[u].z*xv.z; a3 += wr[u].w*xv.w;
            }
            float g = (a0+a1)+(a2+a3) + bias;
            if (mat) gh[j] = g; else gi[j] = g;
            __syncthreads();
            if (tid < H_) {
                int m = tid;
                float r = 1.f/(1.f+expf(-(gi[m]      + gh[m])));
                float z = 1.f/(1.f+expf(-(gi[m+128]  + gh[m+128])));
                float n = tanhf(gi[m+256] + r*gh[m+256]);
                float hnew = (1.f-z)*n + z*hh[m];
                hh[m] = hnew; ys[t][m] = hnew;
            }
            __syncthreads();
        }
    }
    if (tid < NC_) {
        float a = pb[tid];
        for (int k = 0; k < H_; k++) a += pw[tid*H_+k]*hh[k];
        out[b*NC_ + tid] = a;
    }
}

extern "C" void kernel_launch(void* const* d_in, const int* in_sizes, int n_in,
                              void* d_out, int out_size, void* d_ws, size_t ws_size,
                              hipStream_t stream) {
    const float* x    = (const float*)d_in[0];
    const float* w0   = (const float*)d_in[1];
    const float* wcs  = (const float*)d_in[2];
    const float* cb   = (const float*)d_in[3];
    const float* bg   = (const float*)d_in[4];
    const float* bb   = (const float*)d_in[5];
    const float* bm   = (const float*)d_in[6];
    const float* bv   = (const float*)d_in[7];
    const float* wq   = (const float*)d_in[8];
    const float* wk   = (const float*)d_in[9];
    const float* wv   = (const float*)d_in[10];
    const float* gam  = (const float*)d_in[11];
    const float* fw   = (const float*)d_in[12];
    const float* fb   = (const float*)d_in[13];
    const float* gwih = (const float*)d_in[14];
    const float* gwhh = (const float*)d_in[15];
    const float* gbih = (const float*)d_in[16];
    const float* gbhh = (const float*)d_in[17];
    const float* pw   = (const float*)d_in[18];
    const float* pb   = (const float*)d_in[19];
    float* out = (float*)d_out;
    uint32_t* wsu = (uint32_t*)d_ws;

    // workspace (4B word offsets):
    // aw   : 0          .. 61,440
    // y1h  : 61,440     .. 15,790,080   (3840 x 16384 B, y2 in-place)
    // y1l  : 15,790,080 .. 31,518,720
    // y3   : 31,518,720 .. 38,645,760
    // xs   : 61,440     (reuses dead y1h region after conv3)
    // seq  : 7,188,480  (after xs, still in dead y1 span)
    // f1   : 14,315,520
    // peak 38,645,760 words = 154.6 MB
    ushort* aw  = (ushort*)wsu;
    char* y1h   = (char*)(wsu + 61440);
    char* y1l   = (char*)(wsu + 15790080);
    float* y3v  = (float*)(wsu + 31518720);
    float* xsv  = (float*)(wsu + 61440);
    float* seqv = (float*)(wsu + 7188480);
    float* f1v  = (float*)(wsu + 14315520);

    prepack_kernel<<<240, 256, 0, stream>>>(wcs, aw);
    conv01_mfma<<<768, 256, 0, stream>>>(x, w0, aw, cb, bg, bb, bm, bv, y1h, y1l);
    conv2_mfma<<<480, 256, 0, stream>>>(aw, cb, bg, bb, bm, bv, y1h, y1l);
    conv3_mfma<<<480, 256, 0, stream>>>(aw, cb, bg, bb, bm, bv, y1h, y1l, y3v);
    transp_kernel<<<2*B_, 256, 0, stream>>>(y3v, xsv);
    attn_kernel<<<N_, 256, 0, stream>>>(xsv, wq, wk, wv, gam, seqv);
    fc1_kernel<<<N_/8, 256, 0, stream>>>(seqv, fw, fb, f1v);
    gru_kernel<<<B_, 768, 0, stream>>>(f1v, gwih, gwhh, gbih, gbhh, pw, pb, out);
}